// Round 7
// baseline (301.929 us; speedup 1.0000x reference)
//
#include <hip/hip_runtime.h>
#include <hip/hip_bf16.h>

#define NN 50000
#define NE 1600000
#define DD 128
#define KC 16

// Buckets of 32 dst-rows: bucket = dst >> 5
#define NB 1563           // ceil(50000/32)
#define NBP (NB + 1)
#define CHUNK 6144        // edges per binsort block
#define NCHUNK 261        // ceil(NE/CHUNK)
#define EPT 12            // CHUNK / 512 edges per thread
#define MAXB 1536         // bucket capacity (avg 1024, sigma ~32)

typedef __attribute__((ext_vector_type(8))) short s8v;   // 8 bf16 = 4 VGPRs
typedef __attribute__((ext_vector_type(4))) float f4v;   // 4 fp32 acc

__device__ __forceinline__ float blo(unsigned u) { return __uint_as_float(u << 16); }
__device__ __forceinline__ float bhi(unsigned u) { return __uint_as_float(u & 0xFFFF0000u); }

// ---------------- chunk-local counting sort by bucket ----------------
// Each block sorts its CHUNK edges by bucket into its PRIVATE window of
// staging2 (chunk-aligned, single-writer -> no cross-XCD line ping-pong).
// Per-chunk bucket start offsets (u16) -> offs[c*NBP + b], offs[c*NBP+NB]=total.

__global__ __launch_bounds__(512) void k_binsort(const int* __restrict__ dst,
                                                 const int* __restrict__ src,
                                                 const float* __restrict__ w,
                                                 int2* __restrict__ staging2,
                                                 unsigned short* __restrict__ offs) {
    __shared__ int cnt[NB];
    __shared__ int s[512];
    int t = threadIdx.x;
    int c = blockIdx.x;
    size_t cbase = (size_t)c * CHUNK;
    for (int i = t; i < NB; i += 512) cnt[i] = 0;
    __syncthreads();

    int dreg[EPT], sreg[EPT]; float wreg[EPT];
    #pragma unroll
    for (int j = 0; j < EPT; j++) {
        size_t e = cbase + j * 512 + t;
        bool ok = e < NE;
        size_t ee = ok ? e : (NE - 1);
        dreg[j] = dst[ee]; sreg[j] = src[ee]; wreg[j] = w[ee];
        if (!ok) dreg[j] = -1;
        if (ok) atomicAdd(&cnt[dreg[j] >> 5], 1);
    }
    __syncthreads();

    // exclusive scan of cnt[0..NB) ; cnt becomes per-bucket cursor start
    int v[4]; int sum = 0;
    #pragma unroll
    for (int j = 0; j < 4; j++) { int i = t * 4 + j; v[j] = (i < NB) ? cnt[i] : 0; sum += v[j]; }
    s[t] = sum; __syncthreads();
    for (int off = 1; off < 512; off <<= 1) {
        int u = (t >= off) ? s[t - off] : 0;
        __syncthreads();
        s[t] += u;
        __syncthreads();
    }
    int run = (t == 0) ? 0 : s[t - 1];
    #pragma unroll
    for (int j = 0; j < 4; j++) {
        int i = t * 4 + j;
        if (i < NB) { offs[(size_t)c * NBP + i] = (unsigned short)run; cnt[i] = run; run += v[j]; }
    }
    if (t == 511) offs[(size_t)c * NBP + NB] = (unsigned short)s[511];
    __syncthreads();

    #pragma unroll
    for (int j = 0; j < EPT; j++) {
        if (dreg[j] >= 0) {
            int b = dreg[j] >> 5;
            int li = atomicAdd(&cnt[b], 1);
            staging2[cbase + li] = make_int2(((dreg[j] & 31) << 16) | sreg[j],
                                            __float_as_int(wreg[j]));
        }
    }
}

// ---------------- per-bucket gather + row sort (done ONCE, reused by both layers) ----------------
// Output: staging[b*MAXB ..] row-sorted records; rowptr[b*33 + r] offsets (rowptr[...32]=cnt).

__global__ __launch_bounds__(256) void k_rowsort(const int2* __restrict__ staging2,
                                                 const unsigned short* __restrict__ offs,
                                                 int2* __restrict__ staging,
                                                 int* __restrict__ rowptr) {
    __shared__ int2 ebuf[MAXB];
    __shared__ int2 ebuf2[MAXB];
    __shared__ int segoff[NCHUNK];
    __shared__ int cstart[NCHUNK];
    __shared__ int s2[256];
    __shared__ int rcnt[32];
    __shared__ int rowoff[33];
    int b = blockIdx.x, t = threadIdx.x;

    // segment lengths per chunk
    for (int c = t; c < NCHUNK; c += 256) {
        int o0 = offs[(size_t)c * NBP + b];
        int o1 = offs[(size_t)c * NBP + b + 1];
        cstart[c] = o0;
        segoff[c] = o1 - o0;   // temporarily holds length
    }
    __syncthreads();
    // exclusive scan of lengths over NCHUNK (2 per thread)
    int a0 = (2 * t < NCHUNK) ? segoff[2 * t] : 0;
    int a1 = (2 * t + 1 < NCHUNK) ? segoff[2 * t + 1] : 0;
    s2[t] = a0 + a1; __syncthreads();
    for (int off = 1; off < 256; off <<= 1) {
        int u = (t >= off) ? s2[t - off] : 0;
        __syncthreads();
        s2[t] += u;
        __syncthreads();
    }
    int base0 = (t == 0) ? 0 : s2[t - 1];
    int total = s2[255];
    __syncthreads();
    if (2 * t < NCHUNK) segoff[2 * t] = base0;
    if (2 * t + 1 < NCHUNK) segoff[2 * t + 1] = base0 + a0;
    __syncthreads();

    int cnt = total; if (cnt > MAXB) cnt = MAXB;

    // gather all segments of this bucket into ebuf
    for (int c = t; c < NCHUNK; c += 256) {
        int so = segoff[c], st = cstart[c];
        int o1 = offs[(size_t)c * NBP + b + 1];
        const int2* sp = staging2 + (size_t)c * CHUNK + st;
        int len = o1 - st;
        for (int j = 0; j < len; j++) {
            int p = so + j;
            if (p < MAXB) ebuf[p] = sp[j];
        }
    }
    __syncthreads();

    // row histogram + scan + scatter
    if (t < 32) rcnt[t] = 0;
    __syncthreads();
    for (int i = t; i < cnt; i += 256) atomicAdd(&rcnt[(unsigned)ebuf[i].x >> 16], 1);
    __syncthreads();
    if (t < 32) {
        int v = rcnt[t];
        int p = v;
        #pragma unroll
        for (int off = 1; off < 32; off <<= 1) {
            int u = __shfl_up(p, off, 64);
            if (t >= off) p += u;
        }
        rowoff[t] = p - v;
        if (t == 31) rowoff[32] = p;
        rcnt[t] = p - v;   // cursor
    }
    __syncthreads();
    for (int i = t; i < cnt; i += 256) {
        int2 rec = ebuf[i];
        int p = atomicAdd(&rcnt[(unsigned)rec.x >> 16], 1);
        ebuf2[p] = rec;
    }
    __syncthreads();

    int2* outp = staging + (size_t)b * MAXB;
    for (int i = t; i < cnt; i += 256) outp[i] = ebuf2[i];
    if (t < 33) rowptr[b * 33 + t] = rowoff[t];
}

// ---------------- W preconvert: fp32 [128][128] -> bf16 frags ----------------

__global__ __launch_bounds__(256) void k_wprep(const float* __restrict__ W,
                                               s8v* __restrict__ Wf) {
    int g = blockIdx.x * 256 + threadIdx.x;   // 2048 threads
    int l = g & 63;
    int kcnt = g >> 6;                         // 0..31
    int kc = kcnt >> 3, nt = kcnt & 7;
    int n = nt * 16 + (l & 15);
    int kb = kc * 32 + (l >> 4) * 8;
    union { s8v v; __hip_bfloat162 h2[4]; } u;
    #pragma unroll
    for (int q = 0; q < 4; q++) {
        float lo = W[(size_t)(kb + 2 * q) * 128 + n];
        float hi = W[(size_t)(kb + 2 * q + 1) * 128 + n];
        u.h2[q] = __float22bfloat162_rn(make_float2(lo, hi));
    }
    Wf[(size_t)kcnt * 64 + l] = u.v;
}

// ---------------- MFMA GEMM: T = bf16( X @ W + bias ), one wave per 32 rows ----------------

__global__ __launch_bounds__(256) void k_gemm_mfma(const float* __restrict__ X,
                                                   const s8v* __restrict__ Wf,
                                                   const float* __restrict__ bias,
                                                   __hip_bfloat16* __restrict__ Out,
                                                   int nrows) {
    int wave = blockIdx.x * 4 + (threadIdx.x >> 6);
    int lane = threadIdx.x & 63;
    int m0 = wave * 32;
    if (m0 >= nrows) return;
    int col = lane & 15;
    int quad = lane >> 4;

    f4v acc[2][8];
    #pragma unroll
    for (int mt = 0; mt < 2; mt++)
        #pragma unroll
        for (int nt = 0; nt < 8; nt++) acc[mt][nt] = (f4v){0.f, 0.f, 0.f, 0.f};

    int row0 = m0 + col;
    int row1 = m0 + 16 + col;
    if (row0 >= nrows) row0 = nrows - 1;
    if (row1 >= nrows) row1 = nrows - 1;
    const float* xr0 = X + (size_t)row0 * 128 + quad * 8;
    const float* xr1 = X + (size_t)row1 * 128 + quad * 8;

    #pragma unroll 1
    for (int kc = 0; kc < 4; kc++) {
        union { s8v v; __hip_bfloat162 h2[4]; } a0, a1;
        {
            float4 f0 = *(const float4*)(xr0 + kc * 32);
            float4 f1 = *(const float4*)(xr0 + kc * 32 + 4);
            a0.h2[0] = __float22bfloat162_rn(make_float2(f0.x, f0.y));
            a0.h2[1] = __float22bfloat162_rn(make_float2(f0.z, f0.w));
            a0.h2[2] = __float22bfloat162_rn(make_float2(f1.x, f1.y));
            a0.h2[3] = __float22bfloat162_rn(make_float2(f1.z, f1.w));
        }
        {
            float4 f0 = *(const float4*)(xr1 + kc * 32);
            float4 f1 = *(const float4*)(xr1 + kc * 32 + 4);
            a1.h2[0] = __float22bfloat162_rn(make_float2(f0.x, f0.y));
            a1.h2[1] = __float22bfloat162_rn(make_float2(f0.z, f0.w));
            a1.h2[2] = __float22bfloat162_rn(make_float2(f1.x, f1.y));
            a1.h2[3] = __float22bfloat162_rn(make_float2(f1.z, f1.w));
        }
        #pragma unroll
        for (int nt = 0; nt < 8; nt++) {
            s8v b = Wf[(size_t)(kc * 8 + nt) * 64 + lane];
            acc[0][nt] = __builtin_amdgcn_mfma_f32_16x16x32_bf16(a0.v, b, acc[0][nt], 0, 0, 0);
            acc[1][nt] = __builtin_amdgcn_mfma_f32_16x16x32_bf16(a1.v, b, acc[1][nt], 0, 0, 0);
        }
    }

    float bb[8];
    #pragma unroll
    for (int nt = 0; nt < 8; nt++) bb[nt] = bias[nt * 16 + col];

    #pragma unroll
    for (int mt = 0; mt < 2; mt++) {
        #pragma unroll
        for (int r = 0; r < 4; r++) {
            int row = m0 + mt * 16 + quad * 4 + r;
            if (row < nrows) {
                __hip_bfloat16* orow = Out + (size_t)row * 128 + col;
                #pragma unroll
                for (int nt = 0; nt < 8; nt++) {
                    orow[nt * 16] = __float2bfloat16(acc[mt][nt][r] + bb[nt]);
                }
            }
        }
    }
}

// ---------------- streaming SPMM + skip + SELU (+ optional softmax-assign) ----------------
// Pre-sorted records: no LDS phase. Quarter-wave gathers, unroll x16 (4KB in flight/wave).

template <int ASSIGN>
__global__ __launch_bounds__(256) void k_spmm(const __hip_bfloat16* __restrict__ T,
                                              const int2* __restrict__ staging,
                                              const int* __restrict__ rowptr,
                                              const float* __restrict__ skip,
                                              float* __restrict__ Hout,
                                              const float* __restrict__ Wa,
                                              const float* __restrict__ ba,
                                              float* __restrict__ aout) {
    int b = blockIdx.x;
    int tid = threadIdx.x;
    int wv = tid >> 6, lane = tid & 63;
    int q = lane >> 4;         // edge-in-batch
    int fk = lane & 15;        // feature group
    const int2* seg = staging + (size_t)b * MAXB;
    const int4* Tv4 = (const int4*)T;   // row = 16 int4 (256 B)

    float sk[8];
    *(float4*)&sk[0] = *(const float4*)(skip + fk * 8);
    *(float4*)&sk[4] = *(const float4*)(skip + fk * 8 + 4);

    float wreg[32];  // ASSIGN: Wa[8fk+j][4q+c]
    float bav[4];
    if (ASSIGN) {
        #pragma unroll
        for (int j = 0; j < 8; j++)
            *(float4*)&wreg[j * 4] = *(const float4*)(Wa + (size_t)(8 * fk + j) * KC + 4 * q);
        #pragma unroll
        for (int c = 0; c < 4; c++) bav[c] = ba[4 * q + c];
    }

    int nrows = NN - b * 32;
    if (nrows > 32) nrows = 32;
    const float scale = 1.0507009873554805f, alpha = 1.6732632423543772f;

    for (int r = wv; r < nrows; r += 4) {
        int g = b * 32 + r;
        int o = rowptr[b * 33 + r];
        int oe = rowptr[b * 33 + r + 1];
        float acc[8];
        #pragma unroll
        for (int j = 0; j < 8; j++) acc[j] = 0.f;

        for (; o + 16 <= oe; o += 16) {     // 4 x 1KB gathers in flight
            int2 r0 = seg[o + q];
            int2 r1 = seg[o + 4 + q];
            int2 r2 = seg[o + 8 + q];
            int2 r3 = seg[o + 12 + q];
            int4 t0 = Tv4[(size_t)(r0.x & 0xFFFF) * 16 + fk];
            int4 t1 = Tv4[(size_t)(r1.x & 0xFFFF) * 16 + fk];
            int4 t2 = Tv4[(size_t)(r2.x & 0xFFFF) * 16 + fk];
            int4 t3 = Tv4[(size_t)(r3.x & 0xFFFF) * 16 + fk];
            float w0 = __int_as_float(r0.y), w1 = __int_as_float(r1.y);
            float w2 = __int_as_float(r2.y), w3 = __int_as_float(r3.y);
            acc[0] += w0 * blo(t0.x); acc[1] += w0 * bhi(t0.x);
            acc[2] += w0 * blo(t0.y); acc[3] += w0 * bhi(t0.y);
            acc[4] += w0 * blo(t0.z); acc[5] += w0 * bhi(t0.z);
            acc[6] += w0 * blo(t0.w); acc[7] += w0 * bhi(t0.w);
            acc[0] += w1 * blo(t1.x); acc[1] += w1 * bhi(t1.x);
            acc[2] += w1 * blo(t1.y); acc[3] += w1 * bhi(t1.y);
            acc[4] += w1 * blo(t1.z); acc[5] += w1 * bhi(t1.z);
            acc[6] += w1 * blo(t1.w); acc[7] += w1 * bhi(t1.w);
            acc[0] += w2 * blo(t2.x); acc[1] += w2 * bhi(t2.x);
            acc[2] += w2 * blo(t2.y); acc[3] += w2 * bhi(t2.y);
            acc[4] += w2 * blo(t2.z); acc[5] += w2 * bhi(t2.z);
            acc[6] += w2 * blo(t2.w); acc[7] += w2 * bhi(t2.w);
            acc[0] += w3 * blo(t3.x); acc[1] += w3 * bhi(t3.x);
            acc[2] += w3 * blo(t3.y); acc[3] += w3 * bhi(t3.y);
            acc[4] += w3 * blo(t3.z); acc[5] += w3 * bhi(t3.z);
            acc[6] += w3 * blo(t3.w); acc[7] += w3 * bhi(t3.w);
        }
        for (; o + 8 <= oe; o += 8) {
            int2 r0 = seg[o + q];
            int2 r1 = seg[o + 4 + q];
            int4 t0 = Tv4[(size_t)(r0.x & 0xFFFF) * 16 + fk];
            int4 t1 = Tv4[(size_t)(r1.x & 0xFFFF) * 16 + fk];
            float w0 = __int_as_float(r0.y), w1 = __int_as_float(r1.y);
            acc[0] += w0 * blo(t0.x); acc[1] += w0 * bhi(t0.x);
            acc[2] += w0 * blo(t0.y); acc[3] += w0 * bhi(t0.y);
            acc[4] += w0 * blo(t0.z); acc[5] += w0 * bhi(t0.z);
            acc[6] += w0 * blo(t0.w); acc[7] += w0 * bhi(t0.w);
            acc[0] += w1 * blo(t1.x); acc[1] += w1 * bhi(t1.x);
            acc[2] += w1 * blo(t1.y); acc[3] += w1 * bhi(t1.y);
            acc[4] += w1 * blo(t1.z); acc[5] += w1 * bhi(t1.z);
            acc[6] += w1 * blo(t1.w); acc[7] += w1 * bhi(t1.w);
        }
        for (; o < oe; o += 4) {            // masked tail (staging slack makes reads safe)
            int i0 = o + q;
            int2 r0 = seg[i0];
            int4 t0 = Tv4[(size_t)(r0.x & 0xFFFF) * 16 + fk];
            float w0 = (i0 < oe) ? __int_as_float(r0.y) : 0.f;
            acc[0] += w0 * blo(t0.x); acc[1] += w0 * bhi(t0.x);
            acc[2] += w0 * blo(t0.y); acc[3] += w0 * bhi(t0.y);
            acc[4] += w0 * blo(t0.z); acc[5] += w0 * bhi(t0.z);
            acc[6] += w0 * blo(t0.w); acc[7] += w0 * bhi(t0.w);
        }

        // combine quarters
        #pragma unroll
        for (int j = 0; j < 8; j++) {
            acc[j] += __shfl_xor(acc[j], 16, 64);
            acc[j] += __shfl_xor(acc[j], 32, 64);
        }

        // self + skip + SELU
        int4 ts = Tv4[(size_t)g * 16 + fk];
        float v[8];
        v[0] = sk[0] * blo(ts.x) + acc[0]; v[1] = sk[1] * bhi(ts.x) + acc[1];
        v[2] = sk[2] * blo(ts.y) + acc[2]; v[3] = sk[3] * bhi(ts.y) + acc[3];
        v[4] = sk[4] * blo(ts.z) + acc[4]; v[5] = sk[5] * bhi(ts.z) + acc[5];
        v[6] = sk[6] * blo(ts.w) + acc[6]; v[7] = sk[7] * bhi(ts.w) + acc[7];
        #pragma unroll
        for (int j = 0; j < 8; j++)
            v[j] = scale * (v[j] > 0.f ? v[j] : alpha * (__expf(v[j]) - 1.f));

        if (!ASSIGN) {
            if (q == 0) {
                float4* dp = (float4*)(Hout + (size_t)g * 128 + fk * 8);
                dp[0] = make_float4(v[0], v[1], v[2], v[3]);
                dp[1] = make_float4(v[4], v[5], v[6], v[7]);
            }
        } else {
            float p4[4] = {0.f, 0.f, 0.f, 0.f};
            #pragma unroll
            for (int j = 0; j < 8; j++)
                #pragma unroll
                for (int c = 0; c < 4; c++) p4[c] += v[j] * wreg[j * 4 + c];
            #pragma unroll
            for (int off = 1; off <= 8; off <<= 1)
                #pragma unroll
                for (int c = 0; c < 4; c++) p4[c] += __shfl_xor(p4[c], off, 64);
            #pragma unroll
            for (int c = 0; c < 4; c++) p4[c] += bav[c];
            float m = fmaxf(fmaxf(p4[0], p4[1]), fmaxf(p4[2], p4[3]));
            m = fmaxf(m, __shfl_xor(m, 16, 64));
            m = fmaxf(m, __shfl_xor(m, 32, 64));
            float e0 = __expf(p4[0] - m), e1 = __expf(p4[1] - m);
            float e2 = __expf(p4[2] - m), e3 = __expf(p4[3] - m);
            float s = e0 + e1 + e2 + e3;
            s += __shfl_xor(s, 16, 64);
            s += __shfl_xor(s, 32, 64);
            if (fk < 4) {
                float ev = e0;
                ev = (fk == 1) ? e1 : ev;
                ev = (fk == 2) ? e2 : ev;
                ev = (fk == 3) ? e3 : ev;
                aout[(size_t)g * KC + 4 * q + fk] = ev / s;
            }
        }
    }
}

// ---------------- launch ----------------

extern "C" void kernel_launch(void* const* d_in, const int* in_sizes, int n_in,
                              void* d_out, int out_size, void* d_ws, size_t ws_size,
                              hipStream_t stream) {
    const float* x     = (const float*)d_in[0];
    const int*   eidx  = (const int*)d_in[1];
    const float* ew    = (const float*)d_in[2];
    const float* W1    = (const float*)d_in[3];
    const float* b1    = (const float*)d_in[4];
    const float* skip1 = (const float*)d_in[5];
    const float* W2    = (const float*)d_in[6];
    const float* b2    = (const float*)d_in[7];
    const float* skip2 = (const float*)d_in[8];
    const float* Wa    = (const float*)d_in[9];
    const float* ba    = (const float*)d_in[10];
    float* out = (float*)d_out;

    const int* dst = eidx;
    const int* src = eidx + NE;

    char* ws = (char*)d_ws;
    size_t off = 0;
    __hip_bfloat16* T = (__hip_bfloat16*)(ws + off); off += (size_t)NN * DD * 2;      // 12.8 MB
    float* Hb = (float*)(ws + off);                  off += (size_t)NN * DD * 4;      // 25.6 MB
    // staging2 (chunk-sorted, dead after k_rowsort) aliases Hb (first written in spmm1)
    int2* staging2 = (int2*)Hb;                      // needs 12.83 MB <= 25.6 MB
    int2* staging = (int2*)(ws + off);               off += ((size_t)NB * MAXB + 16) * 8;  // 19.2 MB
    unsigned short* offs = (unsigned short*)(ws + off); off += (size_t)NCHUNK * NBP * 2;   // 816 KB
    int* rowptr = (int*)(ws + off);                  off += (size_t)NB * 33 * 4;      // 206 KB
    s8v* Wf1 = (s8v*)(ws + off);                     off += 2048 * 16;                // 32 KB
    s8v* Wf2 = (s8v*)(ws + off);                     off += 2048 * 16;                // 32 KB

    k_binsort<<<NCHUNK, 512, 0, stream>>>(dst, src, ew, staging2, offs);
    k_rowsort<<<NB, 256, 0, stream>>>(staging2, offs, staging, rowptr);

    k_wprep<<<8, 256, 0, stream>>>(W1, Wf1);
    k_wprep<<<8, 256, 0, stream>>>(W2, Wf2);

    int gemm_grid = (NN / 128) + 1;   // 391 blocks x 4 waves x 32 rows
    // layer 1
    k_gemm_mfma<<<gemm_grid, 256, 0, stream>>>(x, Wf1, b1, T, NN);
    k_spmm<0><<<NB, 256, 0, stream>>>(T, staging, rowptr, skip1, Hb, nullptr, nullptr, nullptr);
    // layer 2
    k_gemm_mfma<<<gemm_grid, 256, 0, stream>>>(Hb, Wf2, b2, T, NN);
    k_spmm<1><<<NB, 256, 0, stream>>>(T, staging, rowptr, skip2, nullptr, Wa, ba, out);
}